// Round 15
// baseline (99.552 us; speedup 1.0000x reference)
//
#include <hip/hip_runtime.h>

typedef _Float16 f16;
typedef _Float16 f16x8 __attribute__((ext_vector_type(8)));
typedef float f32x4 __attribute__((ext_vector_type(4)));

static_assert(sizeof(f16x8) == 16, "f16x8 must be 16B");

#define MFMA16x16x32F(a, b, c) __builtin_amdgcn_mfma_f32_16x16x32_f16((a), (b), (c), 0, 0, 0)

// problem constants
#define NB 2
#define NL 1024
#define ND 1024
#define NH 16
#define NHD 64
#define NP 2047
#define NBH (NB * NH)  // 32

// wave-synchronous LDS fence (wave-private LDS slices): no vmcnt drain
__device__ __forceinline__ void wave_sync_lds() {
  __builtin_amdgcn_sched_barrier(0);
  asm volatile("s_waitcnt lgkmcnt(0)" ::: "memory");
  __builtin_amdgcn_sched_barrier(0);
}

// async global->LDS, 16B per lane, wave-linear dest
__device__ __forceinline__ void gload16(const f16* g, f16* lds) {
  __builtin_amdgcn_global_load_lds((const __attribute__((address_space(1))) void*)g,
                                   (__attribute__((address_space(3))) void*)lds, 16, 0, 0);
}

// ---------------- kernel 0: fused prep — Er frag-pack + X cast + both W transposes ----------------
// blocks [0,8192): er_pack; [8192,16384): X cast; [16384,17408): W transposes.
__global__ __launch_bounds__(256) void prep_all_k(const float* __restrict__ er,
                                                  f16* __restrict__ epf,
                                                  const float* __restrict__ x,
                                                  f16* __restrict__ xf,
                                                  const float* __restrict__ Wqkv,
                                                  f16* __restrict__ WTqkv,
                                                  const float* __restrict__ Wo,
                                                  f16* __restrict__ WTo) {
  const int b = blockIdx.x;
  const int t = threadIdx.x;
  if (b < 8192) {
    const int i = b * 256 + t;  // 2^21 total
    const int e = i & 7;
    const int lane = (i >> 3) & 63;
    const int half = (i >> 9) & 1;
    const int ob = (i >> 10) & 127;
    const int h = i >> 17;
    const int g = lane >> 4, cl = lane & 15;
    const int o = ob * 16 - 1024 + cl;
    const int p = (o <= 0) ? -o : (NP - o);
    const int d = half * 32 + g * 8 + e;
    epf[i] = (f16)er[(size_t)(h * NP + p) * NHD + d];
  } else if (b < 16384) {
    const int i = (b - 8192) * 256 + t;
    xf[i] = (f16)x[i];
  } else {
    __shared__ float tile[64][68];
    const int b2 = b - 16384;           // [0,1024)
    const int bx = b2 >> 4;             // [0,64)
    const int k0 = (b2 & 15) * 64;
    const float* W;
    f16* WT;
    int N, n0;
    if (bx < 48) { W = Wqkv; WT = WTqkv; N = 3072; n0 = bx * 64; }
    else         { W = Wo;   WT = WTo;   N = 1024; n0 = (bx - 48) * 64; }
    const int rc = t & 15;
    const int rr0 = t >> 4;
#pragma unroll
    for (int i = 0; i < 4; ++i) {
      const int row = rr0 + i * 16;
      float4 v = *(const float4*)(W + (size_t)(k0 + row) * N + n0 + rc * 4);
      *(float4*)&tile[row][rc * 4] = v;
    }
    __syncthreads();
    const int n = t >> 2, kc = (t & 3) * 16;
    f16x8 h0, h1;
#pragma unroll
    for (int e = 0; e < 8; ++e) h0[e] = (f16)tile[kc + e][n];
#pragma unroll
    for (int e = 0; e < 8; ++e) h1[e] = (f16)tile[kc + 8 + e][n];
    f16* dst = WT + (size_t)(n0 + n) * ND + k0 + kc;
    *(f16x8*)dst = h0;
    *(f16x8*)(dst + 8) = h1;
  }
}

// ---------------- kernel 1: QKV projection GEMM (f16, 64x128 tile, BK=64 as 2x32 sub-tiles) ----------------
__global__ __launch_bounds__(256) void qkv_gemm_k(const f16* __restrict__ Xf,
                                                  const f16* __restrict__ WT,
                                                  const float* __restrict__ bias,
                                                  f16* __restrict__ qf,
                                                  f16* __restrict__ kp, f16* __restrict__ vp) {
  __shared__ f16 sA[2][64 * 32], sB[2][128 * 32];  // 24 KB
  const int t = threadIdx.x;
  const int lane = t & 63;
  const int w = t >> 6;
  const int cl = lane & 15;
  const int g = lane >> 4;
  const int m0 = blockIdx.y * 64;
  const int n0 = blockIdx.x * 128;

  const int arow = w * 16 + (lane >> 2);
  const int brow0 = w * 32 + (lane >> 2);
  const int scol = ((lane & 3) ^ ((lane >> 3) & 3)) * 8;  // T2 source swizzle
  const int rsw = (g ^ ((cl >> 1) & 3)) * 8;              // swizzled read col

  f32x4 acc[4][2] = {};

  for (int k0 = 0; k0 < ND; k0 += 64) {
#pragma unroll
    for (int kc = 0; kc < 2; ++kc) {
      const int kk = k0 + kc * 32;
      gload16(Xf + (size_t)(m0 + arow) * ND + kk + scol, &sA[kc][w * 512]);
      const f16* gb0 = WT + (size_t)(n0 + brow0) * ND + kk + scol;
      gload16(gb0, &sB[kc][w * 1024]);
      gload16(gb0 + (size_t)16 * ND, &sB[kc][w * 1024 + 512]);
    }
    __syncthreads();

#pragma unroll
    for (int kc = 0; kc < 2; ++kc) {
      f16x8 ah[4], bh[2];
#pragma unroll
      for (int fm = 0; fm < 4; ++fm) ah[fm] = *(const f16x8*)&sA[kc][(fm * 16 + cl) * 32 + rsw];
#pragma unroll
      for (int fn = 0; fn < 2; ++fn) bh[fn] = *(const f16x8*)&sB[kc][(w * 32 + fn * 16 + cl) * 32 + rsw];
#pragma unroll
      for (int fm = 0; fm < 4; ++fm)
#pragma unroll
        for (int fn = 0; fn < 2; ++fn)
          acc[fm][fn] = MFMA16x16x32F(ah[fm], bh[fn], acc[fm][fn]);
    }
    __syncthreads();
  }

  // epilogue: bias + scatter into attention layouts (all f16)
#pragma unroll
  for (int fm = 0; fm < 4; ++fm) {
#pragma unroll
    for (int fn = 0; fn < 2; ++fn) {
#pragma unroll
      for (int reg = 0; reg < 4; ++reg) {
        const int gm = m0 + fm * 16 + g * 4 + reg;       // token row
        const int gn = n0 + w * 32 + fn * 16 + cl;       // qkv col
        float val = acc[fm][fn][reg] + bias[gn];
        const int bb = gm >> 10, lpos = gm & 1023;
        const int sec = gn >> 10, hc = gn & 1023;
        const int hh = hc >> 6, dd = hc & 63;
        const int bh = bb * NH + hh;
        if (sec == 0) {
          qf[(size_t)(bh * NL + lpos) * NHD + dd] = (f16)val;
        } else if (sec == 1) {
          const size_t idx = ((size_t)((bh * 64 + (lpos >> 4)) * 2 + (dd >> 5))) * 512 +
                             ((((dd >> 3) & 3) << 4) + (lpos & 15)) * 8 + (dd & 7);
          kp[idx] = (f16)val;
        } else {
          const size_t idx = ((size_t)(((bh * 16 + (lpos >> 6)) * 4 + (dd >> 4)) * 2 +
                                       ((lpos >> 5) & 1))) * 512 +
                             ((((lpos >> 3) & 3) << 4) + (dd & 15)) * 8 + (lpos & 7);
          vp[idx] = (f16)val;
        }
      }
    }
  }
}

// ---------------- kernel 2: attention, v12 (QBLK=32: two 16-row tiles share K/V/E loads) ----------------
__global__ __launch_bounds__(256) void attn_k(const f16* __restrict__ qf,
                                              const f16* __restrict__ kp, const f16* __restrict__ vp,
                                              const f16* __restrict__ epf,
                                              f16* __restrict__ ao) {
  __shared__ float s_lds[4][2][16][67];  // [wave][tile][row][col]; reused as obuf in merge
  __shared__ float mb[4][2][16], lbuf[4][2][16], linv[2][16];

  const int t = threadIdx.x;
  const int w = t >> 6;
  const int lane = t & 63;
  const int cl = lane & 15;
  const int g = lane >> 4;

  const int n = blockIdx.x;               // 1024 blocks
  const int xcd = n & 7, idx = n >> 3;    // idx in [0,128)
  const int bh = (xcd << 2) | (idx >> 5);
  const int itp = 31 - (idx & 31);        // long blocks first
  const int i0A = itp * 32, i0B = i0A + 16;
  const int h = bh & (NH - 1);
  const int nchunks = (i0B >> 6) + 1;

  const f16* qAp = qf + (size_t)(bh * NL + i0A + cl) * NHD + g * 8;
  const f16* qBp = qf + (size_t)(bh * NL + i0B + cl) * NHD + g * 8;
  const f16x8 q_a0 = *(const f16x8*)qAp;
  const f16x8 q_a1 = *(const f16x8*)(qAp + 32);
  const f16x8 q_b0 = *(const f16x8*)qBp;
  const f16x8 q_b1 = *(const f16x8*)(qBp + 32);

  f32x4 acc_oA[4] = {}, acc_oB[4] = {};
  float mA = -3e38f, lA = 0.0f, mB = -3e38f, lB = 0.0f;

  for (int jc = w; jc < nchunks; jc += 4) {
    const int j0 = jc * 64;
    const int deltaA = i0A - j0;   // >= 0, multiple of 16 (proof: i0A mod 64 in {0,32})
    const int deltaB = deltaA + 16;

    // ---- S = Q K^T for both tiles (K loaded once) ----
    const f16* kbase = kp + ((size_t)(bh * 64 + (j0 >> 4)) * 2) * 512 + lane * 8;
    f32x4 accsA[4], accsB[4];
    __builtin_amdgcn_s_setprio(1);
#pragma unroll
    for (int jn = 0; jn < 4; ++jn) {
      f16x8 kf0 = *(const f16x8*)(kbase + (jn * 2 + 0) * 512);
      f16x8 kf1 = *(const f16x8*)(kbase + (jn * 2 + 1) * 512);
      f32x4 a = {};
      a = MFMA16x16x32F(q_a0, kf0, a);
      a = MFMA16x16x32F(q_a1, kf1, a);
      accsA[jn] = a;
      f32x4 bsum = {};
      bsum = MFMA16x16x32F(q_b0, kf0, bsum);
      bsum = MFMA16x16x32F(q_b1, kf1, bsum);
      accsB[jn] = bsum;
    }

    // ---- bias: 6 shared Er tile loads; A uses tiles 0-4, B uses tiles 1-5 ----
    const int ob0 = (deltaA >> 4) + 60;
    const f16* ebase = epf + ((size_t)(h * 128 + ob0) * 2) * 512 + lane * 8;
    f32x4 accEA[5], accEB[5];
#pragma unroll
    for (int tt = 0; tt < 6; ++tt) {
      f16x8 ef0 = *(const f16x8*)(ebase + (tt * 2 + 0) * 512);
      f16x8 ef1 = *(const f16x8*)(ebase + (tt * 2 + 1) * 512);
      if (tt < 5) {
        f32x4 c = {};
        c = MFMA16x16x32F(q_a0, ef0, c);
        c = MFMA16x16x32F(q_a1, ef1, c);
        accEA[tt] = c;
      }
      if (tt >= 1) {
        f32x4 c = {};
        c = MFMA16x16x32F(q_b0, ef0, c);
        c = MFMA16x16x32F(q_b1, ef1, c);
        accEB[tt - 1] = c;
      }
    }
    __builtin_amdgcn_s_setprio(0);

    // ---- V fragments (shared by both PVs) ----
    const f16* vbase = vp + ((size_t)(bh * 16 + (j0 >> 6)) * 8) * 512 + lane * 8;
    f16x8 vf[4][2];
#pragma unroll
    for (int t4 = 0; t4 < 4; ++t4) {
      vf[t4][0] = *(const f16x8*)(vbase + (t4 * 2 + 0) * 512);
      vf[t4][1] = *(const f16x8*)(vbase + (t4 * 2 + 1) * 512);
    }

    // ---- diagonal gather of E into S; spill both tiles, one fence ----
#pragma unroll
    for (int reg = 0; reg < 4; ++reg) {
      const int r = g * 4 + reg;
      const int src = (g << 4) | ((r - cl) & 15);
      const bool ge = (r >= cl);
#pragma unroll
      for (int jn = 0; jn < 4; ++jn) {
        float eA_hi = __shfl(accEA[4 - jn][reg], src);
        float eA_lo = __shfl(accEA[3 - jn][reg], src);
        s_lds[w][0][r][jn * 16 + cl] = fmaf(accsA[jn][reg], 0.125f, ge ? eA_hi : eA_lo);
        float eB_hi = __shfl(accEB[4 - jn][reg], src);
        float eB_lo = __shfl(accEB[3 - jn][reg], src);
        s_lds[w][1][r][jn * 16 + cl] = fmaf(accsB[jn][reg], 0.125f, ge ? eB_hi : eB_lo);
      }
    }
    wave_sync_lds();

    // ---- softmax + PV, tile A ----
    {
      float sv[16];
      float tmax = -3e38f;
#pragma unroll
      for (int cc = 0; cc < 16; ++cc) {
        const int c = (cc < 8) ? (g * 8 + cc) : (32 + g * 8 + (cc - 8));
        float v = s_lds[w][0][cl][c];
        if (c > deltaA + cl) v = -3e38f;
        sv[cc] = v;
        tmax = fmaxf(tmax, v);
      }
      tmax = fmaxf(tmax, __shfl_xor(tmax, 16));
      tmax = fmaxf(tmax, __shfl_xor(tmax, 32));
      const float m_new = fmaxf(mA, tmax);
      const float fsc = __builtin_amdgcn_exp2f((mA - m_new) * 1.44269504f);
      float psum = 0.0f;
      f16x8 pf0, pf1;
#pragma unroll
      for (int cc = 0; cc < 16; ++cc) {
        float pv = __builtin_amdgcn_exp2f((sv[cc] - m_new) * 1.44269504f);
        psum += pv;
        if (cc < 8) pf0[cc & 7] = (f16)pv;
        else        pf1[cc & 7] = (f16)pv;
      }
      psum += __shfl_xor(psum, 16);
      psum += __shfl_xor(psum, 32);
      lA = lA * fsc + psum;
      mA = m_new;
      float fr[4];
#pragma unroll
      for (int reg = 0; reg < 4; ++reg) fr[reg] = __shfl(fsc, g * 4 + reg);
#pragma unroll
      for (int t4 = 0; t4 < 4; ++t4) {
#pragma unroll
        for (int reg = 0; reg < 4; ++reg) acc_oA[t4][reg] *= fr[reg];
      }
      __builtin_amdgcn_s_setprio(1);
#pragma unroll
      for (int t4 = 0; t4 < 4; ++t4) {
        acc_oA[t4] = MFMA16x16x32F(pf0, vf[t4][0], acc_oA[t4]);
        acc_oA[t4] = MFMA16x16x32F(pf1, vf[t4][1], acc_oA[t4]);
      }
      __builtin_amdgcn_s_setprio(0);
    }

    // ---- softmax + PV, tile B ----
    {
      float sv[16];
      float tmax = -3e38f;
#pragma unroll
      for (int cc = 0; cc < 16; ++cc) {
        const int c = (cc < 8) ? (g * 8 + cc) : (32 + g * 8 + (cc - 8));
        float v = s_lds[w][1][cl][c];
        if (c > deltaB + cl) v = -3e38f;
        sv[cc] = v;
        tmax = fmaxf(tmax, v);
      }
      tmax = fmaxf(tmax, __shfl_xor(tmax, 16));
      tmax = fmaxf(tmax, __shfl_xor(tmax, 32));
      const float m_new = fmaxf(mB, tmax);
      const float fsc = __builtin_amdgcn_exp2f((mB - m_new) * 1.44269504f);
      float psum = 0.0f;
      f16x8 pf0, pf1;
#pragma unroll
      for (int cc = 0; cc < 16; ++cc) {
        float pv = __builtin_amdgcn_exp2f((sv[cc] - m_new) * 1.44269504f);
        psum += pv;
        if (cc < 8) pf0[cc & 7] = (f16)pv;
        else        pf1[cc & 7] = (f16)pv;
      }
      psum += __shfl_xor(psum, 16);
      psum += __shfl_xor(psum, 32);
      lB = lB * fsc + psum;
      mB = m_new;
      float fr[4];
#pragma unroll
      for (int reg = 0; reg < 4; ++reg) fr[reg] = __shfl(fsc, g * 4 + reg);
#pragma unroll
      for (int t4 = 0; t4 < 4; ++t4) {
#pragma unroll
        for (int reg = 0; reg < 4; ++reg) acc_oB[t4][reg] *= fr[reg];
      }
      __builtin_amdgcn_s_setprio(1);
#pragma unroll
      for (int t4 = 0; t4 < 4; ++t4) {
        acc_oB[t4] = MFMA16x16x32F(pf0, vf[t4][0], acc_oB[t4]);
        acc_oB[t4] = MFMA16x16x32F(pf1, vf[t4][1], acc_oB[t4]);
      }
      __builtin_amdgcn_s_setprio(0);
    }
  }

  // ---- flash-merge the 4 waves' partials for both tiles ----
  if (lane < 16) {
    mb[w][0][lane] = mA;
    lbuf[w][0][lane] = lA;
    mb[w][1][lane] = mB;
    lbuf[w][1][lane] = lB;
  }
  __syncthreads();
  {
    const float M = fmaxf(fmaxf(mb[0][0][cl], mb[1][0][cl]), fmaxf(mb[2][0][cl], mb[3][0][cl]));
    const float sc = __builtin_amdgcn_exp2f((mA - M) * 1.44269504f);
    float Lt = 0.0f;
#pragma unroll
    for (int ww = 0; ww < 4; ++ww)
      Lt += lbuf[ww][0][cl] * __builtin_amdgcn_exp2f((mb[ww][0][cl] - M) * 1.44269504f);
    if (w == 0 && lane < 16) linv[0][lane] = 1.0f / Lt;
    float fr2[4];
#pragma unroll
    for (int reg = 0; reg < 4; ++reg) fr2[reg] = __shfl(sc, g * 4 + reg);
#pragma unroll
    for (int t4 = 0; t4 < 4; ++t4) {
#pragma unroll
      for (int reg = 0; reg < 4; ++reg)
        s_lds[w][0][g * 4 + reg][t4 * 16 + cl] = acc_oA[t4][reg] * fr2[reg];
    }
  }
  {
    const float M = fmaxf(fmaxf(mb[0][1][cl], mb[1][1][cl]), fmaxf(mb[2][1][cl], mb[3][1][cl]));
    const float sc = __builtin_amdgcn_exp2f((mB - M) * 1.44269504f);
    float Lt = 0.0f;
#pragma unroll
    for (int ww = 0; ww < 4; ++ww)
      Lt += lbuf[ww][1][cl] * __builtin_amdgcn_exp2f((mb[ww][1][cl] - M) * 1.44269504f);
    if (w == 0 && lane < 16) linv[1][lane] = 1.0f / Lt;
    float fr2[4];
#pragma unroll
    for (int reg = 0; reg < 4; ++reg) fr2[reg] = __shfl(sc, g * 4 + reg);
#pragma unroll
    for (int t4 = 0; t4 < 4; ++t4) {
#pragma unroll
      for (int reg = 0; reg < 4; ++reg)
        s_lds[w][1][g * 4 + reg][t4 * 16 + cl] = acc_oB[t4][reg] * fr2[reg];
    }
  }
  __syncthreads();
  const int bb = bh >> 4;  // NH == 16
#pragma unroll
  for (int rep = 0; rep < 8; ++rep) {
    const int o_ = t + rep * 256;
    const int r32 = o_ >> 6, c = o_ & 63;
    const int tl = r32 >> 4, r = r32 & 15;
    float s = s_lds[0][tl][r][c] + s_lds[1][tl][r][c] + s_lds[2][tl][r][c] + s_lds[3][tl][r][c];
    ao[(size_t)(bb * NL + i0A + r32) * ND + h * NHD + c] = (f16)(s * linv[tl][r]);
  }
}

// ---------------- kernel 3: output projection (f16, 64x128 tile, BK=64, T2 swizzle) ----------------
__global__ __launch_bounds__(256) void out_gemm_k(const f16* __restrict__ A,
                                                  const f16* __restrict__ WT,
                                                  const float* __restrict__ bias,
                                                  float* __restrict__ out) {
  __shared__ f16 sA[2][64 * 32], sB[2][128 * 32];
  const int t = threadIdx.x;
  const int lane = t & 63, w = t >> 6;
  const int cl = lane & 15, g = lane >> 4;
  const int m0 = blockIdx.x * 64;
  const int n0 = blockIdx.y * 128;

  const int arow = w * 16 + (lane >> 2);
  const int brow0 = w * 32 + (lane >> 2);
  const int scol = ((lane & 3) ^ ((lane >> 3) & 3)) * 8;
  const int rsw = (g ^ ((cl >> 1) & 3)) * 8;

  f32x4 acc[4][2] = {};

  for (int k0 = 0; k0 < ND; k0 += 64) {
#pragma unroll
    for (int kc = 0; kc < 2; ++kc) {
      const int kk = k0 + kc * 32;
      gload16(A + (size_t)(m0 + arow) * ND + kk + scol, &sA[kc][w * 512]);
      const f16* gb0 = WT + (size_t)(n0 + brow0) * ND + kk + scol;
      gload16(gb0, &sB[kc][w * 1024]);
      gload16(gb0 + (size_t)16 * ND, &sB[kc][w * 1024 + 512]);
    }
    __syncthreads();
#pragma unroll
    for (int kc = 0; kc < 2; ++kc) {
      f16x8 ah[4], bh[2];
#pragma unroll
      for (int fm = 0; fm < 4; ++fm) ah[fm] = *(const f16x8*)&sA[kc][(fm * 16 + cl) * 32 + rsw];
#pragma unroll
      for (int fn = 0; fn < 2; ++fn) bh[fn] = *(const f16x8*)&sB[kc][(w * 32 + fn * 16 + cl) * 32 + rsw];
#pragma unroll
      for (int fm = 0; fm < 4; ++fm)
#pragma unroll
        for (int fn = 0; fn < 2; ++fn)
          acc[fm][fn] = MFMA16x16x32F(ah[fm], bh[fn], acc[fm][fn]);
    }
    __syncthreads();
  }
#pragma unroll
  for (int fm = 0; fm < 4; ++fm) {
#pragma unroll
    for (int fn = 0; fn < 2; ++fn) {
#pragma unroll
      for (int reg = 0; reg < 4; ++reg) {
        const int gm = m0 + fm * 16 + g * 4 + reg;
        const int gn = n0 + w * 32 + fn * 16 + cl;
        out[(size_t)gm * ND + gn] = acc[fm][fn][reg] + bias[gn];
      }
    }
  }
}

extern "C" void kernel_launch(void* const* d_in, const int* in_sizes, int n_in,
                              void* d_out, int out_size, void* d_ws, size_t ws_size,
                              hipStream_t stream) {
  (void)in_sizes; (void)n_in; (void)out_size; (void)ws_size;
  const float* x = (const float*)d_in[0];
  // d_in[1] = causal mask — structural (triu k=1), computed inline
  const float* Wqkv = (const float*)d_in[2];
  const float* bqkv = (const float*)d_in[3];
  const float* Wo = (const float*)d_in[4];
  const float* bo = (const float*)d_in[5];
  const float* Er = (const float*)d_in[6];

  char* ws = (char*)d_ws;
  size_t off = 0;
  auto take = [&](size_t bytes) {
    char* p = ws + off;
    off += (bytes + 255) & ~(size_t)255;
    return p;
  };
  const size_t qkN = (size_t)NBH * NL * NHD;       // 2,097,152
  const size_t xN = (size_t)NB * NL * ND;          // 2,097,152
  const size_t erpN = (size_t)NH * 128 * 2 * 512;  // 2,097,152
  f16* epf = (f16*)take(erpN * 2);
  f16* qfw = (f16*)take(qkN * 2);
  f16* kpw = (f16*)take(qkN * 2);    // K frag-packed
  f16* vpw = (f16*)take(qkN * 2);    // V frag-packed
  f16* wqkvt = (f16*)take((size_t)3 * ND * ND * 2);  // [3072][1024]
  f16* wot   = (f16*)take((size_t)ND * ND * 2);      // [1024][1024]
  f16* xf    = (f16*)take(xN * 2);                   // X f16
  f16* aow = wqkvt;  // alias: wqkvt dead after qkv_gemm, aow born in attn

  prep_all_k<<<17408, 256, 0, stream>>>(Er, epf, x, xf, Wqkv, wqkvt, Wo, wot);
  qkv_gemm_k<<<dim3(24, 32), 256, 0, stream>>>(xf, wqkvt, bqkv, qfw, kpw, vpw);
  attn_k<<<1024, 256, 0, stream>>>(qfw, kpw, vpw, epf, aow);
  out_gemm_k<<<dim3(32, 8), 256, 0, stream>>>(aow, wot, bo, (float*)d_out);
}

// Round 16
// 85.316 us; speedup vs baseline: 1.1669x; 1.1669x over previous
//
#include <hip/hip_runtime.h>

typedef _Float16 f16;
typedef _Float16 f16x8 __attribute__((ext_vector_type(8)));
typedef float f32x4 __attribute__((ext_vector_type(4)));

static_assert(sizeof(f16x8) == 16, "f16x8 must be 16B");

#define MFMA16x16x32F(a, b, c) __builtin_amdgcn_mfma_f32_16x16x32_f16((a), (b), (c), 0, 0, 0)

// problem constants
#define NB 2
#define NL 1024
#define ND 1024
#define NH 16
#define NHD 64
#define NP 2047
#define NBH (NB * NH)  // 32

// wave-synchronous LDS fence: waitcnt only (no sched_barrier) — post-fence MFMAs
// depend on ds_read results via true data deps, so scheduler fences are not needed;
// removing them lets the compiler hoist next-chunk global loads above the tail.
__device__ __forceinline__ void wave_sync_lds() {
  asm volatile("s_waitcnt lgkmcnt(0)" ::: "memory");
}

// async global->LDS, 16B per lane, wave-linear dest
__device__ __forceinline__ void gload16(const f16* g, f16* lds) {
  __builtin_amdgcn_global_load_lds((const __attribute__((address_space(1))) void*)g,
                                   (__attribute__((address_space(3))) void*)lds, 16, 0, 0);
}

// ---------------- kernel 0: fused prep — Er frag-pack + X cast + both W transposes ----------------
// blocks [0,8192): er_pack; [8192,16384): X cast; [16384,17408): W transposes.
__global__ __launch_bounds__(256) void prep_all_k(const float* __restrict__ er,
                                                  f16* __restrict__ epf,
                                                  const float* __restrict__ x,
                                                  f16* __restrict__ xf,
                                                  const float* __restrict__ Wqkv,
                                                  f16* __restrict__ WTqkv,
                                                  const float* __restrict__ Wo,
                                                  f16* __restrict__ WTo) {
  const int b = blockIdx.x;
  const int t = threadIdx.x;
  if (b < 8192) {
    const int i = b * 256 + t;  // 2^21 total
    const int e = i & 7;
    const int lane = (i >> 3) & 63;
    const int half = (i >> 9) & 1;
    const int ob = (i >> 10) & 127;
    const int h = i >> 17;
    const int g = lane >> 4, cl = lane & 15;
    const int o = ob * 16 - 1024 + cl;
    const int p = (o <= 0) ? -o : (NP - o);
    const int d = half * 32 + g * 8 + e;
    epf[i] = (f16)er[(size_t)(h * NP + p) * NHD + d];
  } else if (b < 16384) {
    const int i = (b - 8192) * 256 + t;
    xf[i] = (f16)x[i];
  } else {
    __shared__ float tile[64][68];
    const int b2 = b - 16384;           // [0,1024)
    const int bx = b2 >> 4;             // [0,64)
    const int k0 = (b2 & 15) * 64;
    const float* W;
    f16* WT;
    int N, n0;
    if (bx < 48) { W = Wqkv; WT = WTqkv; N = 3072; n0 = bx * 64; }
    else         { W = Wo;   WT = WTo;   N = 1024; n0 = (bx - 48) * 64; }
    const int rc = t & 15;
    const int rr0 = t >> 4;
#pragma unroll
    for (int i = 0; i < 4; ++i) {
      const int row = rr0 + i * 16;
      float4 v = *(const float4*)(W + (size_t)(k0 + row) * N + n0 + rc * 4);
      *(float4*)&tile[row][rc * 4] = v;
    }
    __syncthreads();
    const int n = t >> 2, kc = (t & 3) * 16;
    f16x8 h0, h1;
#pragma unroll
    for (int e = 0; e < 8; ++e) h0[e] = (f16)tile[kc + e][n];
#pragma unroll
    for (int e = 0; e < 8; ++e) h1[e] = (f16)tile[kc + 8 + e][n];
    f16* dst = WT + (size_t)(n0 + n) * ND + k0 + kc;
    *(f16x8*)dst = h0;
    *(f16x8*)(dst + 8) = h1;
  }
}

// ---------------- kernel 1: QKV projection GEMM (f16, 64x128 tile, BK=64 as 2x32 sub-tiles) ----------------
__global__ __launch_bounds__(256) void qkv_gemm_k(const f16* __restrict__ Xf,
                                                  const f16* __restrict__ WT,
                                                  const float* __restrict__ bias,
                                                  f16* __restrict__ qf,
                                                  f16* __restrict__ kp, f16* __restrict__ vp) {
  __shared__ f16 sA[2][64 * 32], sB[2][128 * 32];  // 24 KB
  const int t = threadIdx.x;
  const int lane = t & 63;
  const int w = t >> 6;
  const int cl = lane & 15;
  const int g = lane >> 4;
  const int m0 = blockIdx.y * 64;
  const int n0 = blockIdx.x * 128;

  const int arow = w * 16 + (lane >> 2);
  const int brow0 = w * 32 + (lane >> 2);
  const int scol = ((lane & 3) ^ ((lane >> 3) & 3)) * 8;  // T2 source swizzle
  const int rsw = (g ^ ((cl >> 1) & 3)) * 8;              // swizzled read col

  f32x4 acc[4][2] = {};

  for (int k0 = 0; k0 < ND; k0 += 64) {
#pragma unroll
    for (int kc = 0; kc < 2; ++kc) {
      const int kk = k0 + kc * 32;
      gload16(Xf + (size_t)(m0 + arow) * ND + kk + scol, &sA[kc][w * 512]);
      const f16* gb0 = WT + (size_t)(n0 + brow0) * ND + kk + scol;
      gload16(gb0, &sB[kc][w * 1024]);
      gload16(gb0 + (size_t)16 * ND, &sB[kc][w * 1024 + 512]);
    }
    __syncthreads();

#pragma unroll
    for (int kc = 0; kc < 2; ++kc) {
      f16x8 ah[4], bh[2];
#pragma unroll
      for (int fm = 0; fm < 4; ++fm) ah[fm] = *(const f16x8*)&sA[kc][(fm * 16 + cl) * 32 + rsw];
#pragma unroll
      for (int fn = 0; fn < 2; ++fn) bh[fn] = *(const f16x8*)&sB[kc][(w * 32 + fn * 16 + cl) * 32 + rsw];
#pragma unroll
      for (int fm = 0; fm < 4; ++fm)
#pragma unroll
        for (int fn = 0; fn < 2; ++fn)
          acc[fm][fn] = MFMA16x16x32F(ah[fm], bh[fn], acc[fm][fn]);
    }
    __syncthreads();
  }

  // epilogue: bias + scatter into attention layouts (all f16)
#pragma unroll
  for (int fm = 0; fm < 4; ++fm) {
#pragma unroll
    for (int fn = 0; fn < 2; ++fn) {
#pragma unroll
      for (int reg = 0; reg < 4; ++reg) {
        const int gm = m0 + fm * 16 + g * 4 + reg;       // token row
        const int gn = n0 + w * 32 + fn * 16 + cl;       // qkv col
        float val = acc[fm][fn][reg] + bias[gn];
        const int bb = gm >> 10, lpos = gm & 1023;
        const int sec = gn >> 10, hc = gn & 1023;
        const int hh = hc >> 6, dd = hc & 63;
        const int bh = bb * NH + hh;
        if (sec == 0) {
          qf[(size_t)(bh * NL + lpos) * NHD + dd] = (f16)val;
        } else if (sec == 1) {
          const size_t idx = ((size_t)((bh * 64 + (lpos >> 4)) * 2 + (dd >> 5))) * 512 +
                             ((((dd >> 3) & 3) << 4) + (lpos & 15)) * 8 + (dd & 7);
          kp[idx] = (f16)val;
        } else {
          const size_t idx = ((size_t)(((bh * 16 + (lpos >> 6)) * 4 + (dd >> 4)) * 2 +
                                       ((lpos >> 5) & 1))) * 512 +
                             ((((lpos >> 3) & 3) << 4) + (dd & 15)) * 8 + (lpos & 7);
          vp[idx] = (f16)val;
        }
      }
    }
  }
}

// ---------------- kernel 2: attention, v11 (R14-proven) + relaxed fence ----------------
__global__ __launch_bounds__(256) void attn_k(const f16* __restrict__ qf,
                                              const f16* __restrict__ kp, const f16* __restrict__ vp,
                                              const f16* __restrict__ epf,
                                              f16* __restrict__ ao) {
  __shared__ float s_lds[4][16][67];
  __shared__ float mb[4][16], lbuf[4][16], linv[16];

  const int t = threadIdx.x;
  const int w = t >> 6;
  const int lane = t & 63;
  const int cl = lane & 15;
  const int g = lane >> 4;

  const int n = blockIdx.x;
  const int xcd = n & 7, idx = n >> 3;
  const int bh = (xcd << 2) | (idx >> 6);
  const int itile = 63 - (idx & 63);
  const int i0 = itile * 16;
  const int h = bh & (NH - 1);
  const int nchunks = (itile >> 2) + 1;

  const f16* qfb = qf + (size_t)(bh * NL + i0 + cl) * NHD + g * 8;
  const f16x8 q_f0 = *(const f16x8*)qfb;
  const f16x8 q_f1 = *(const f16x8*)(qfb + 32);

  f32x4 acc_o[4] = {};
  float m_s = -3e38f, l_s = 0.0f;

  for (int jc = w; jc < nchunks; jc += 4) {
    const int j0 = jc * 64;
    const int delta = i0 - j0;

    // ---- V fragments (contiguous 1KB streams) ----
    const f16* vbase = vp + ((size_t)(bh * 16 + (j0 >> 6)) * 8) * 512 + lane * 8;
    f16x8 vf[4][2];
#pragma unroll
    for (int t4 = 0; t4 < 4; ++t4) {
      vf[t4][0] = *(const f16x8*)(vbase + (t4 * 2 + 0) * 512);
      vf[t4][1] = *(const f16x8*)(vbase + (t4 * 2 + 1) * 512);
    }

    // ---- S = Q K^T ----
    const f16* kbase = kp + ((size_t)(bh * 64 + (j0 >> 4)) * 2) * 512 + lane * 8;
    f32x4 acc_s[4];
    __builtin_amdgcn_s_setprio(1);
#pragma unroll
    for (int jn = 0; jn < 4; ++jn) {
      f16x8 kf0 = *(const f16x8*)(kbase + (jn * 2 + 0) * 512);
      f16x8 kf1 = *(const f16x8*)(kbase + (jn * 2 + 1) * 512);
      f32x4 a = {};
      a = MFMA16x16x32F(q_f0, kf0, a);
      a = MFMA16x16x32F(q_f1, kf1, a);
      acc_s[jn] = a;
    }

    // ---- bias: 5 Er tiles ----
    const int ob0 = (delta >> 4) + 60;
    const f16* ebase = epf + ((size_t)(h * 128 + ob0) * 2) * 512 + lane * 8;
    f32x4 acc_e[5];
#pragma unroll
    for (int tt = 0; tt < 5; ++tt) {
      f16x8 ef0 = *(const f16x8*)(ebase + (tt * 2 + 0) * 512);
      f16x8 ef1 = *(const f16x8*)(ebase + (tt * 2 + 1) * 512);
      f32x4 c = {};
      c = MFMA16x16x32F(q_f0, ef0, c);
      c = MFMA16x16x32F(q_f1, ef1, c);
      acc_e[tt] = c;
    }
    __builtin_amdgcn_s_setprio(0);

    // ---- in-register diagonal gather of E into S; spill combined to LDS ----
#pragma unroll
    for (int reg = 0; reg < 4; ++reg) {
      const int r = g * 4 + reg;
      const int src = (g << 4) | ((r - cl) & 15);
      const bool ge = (r >= cl);
#pragma unroll
      for (int jn = 0; jn < 4; ++jn) {
        float e_hi = __shfl(acc_e[4 - jn][reg], src);
        float e_lo = __shfl(acc_e[3 - jn][reg], src);
        s_lds[w][r][jn * 16 + cl] = fmaf(acc_s[jn][reg], 0.125f, ge ? e_hi : e_lo);
      }
    }
    wave_sync_lds();

    // ---- online softmax; lane (g,cl): row=cl, cols {g*8+cc} U {32+g*8+cc} ----
    float sv[16];
    float tmax = -3e38f;
#pragma unroll
    for (int cc = 0; cc < 16; ++cc) {
      const int c = (cc < 8) ? (g * 8 + cc) : (32 + g * 8 + (cc - 8));
      float v = s_lds[w][cl][c];
      if (c > delta + cl) v = -3e38f;
      sv[cc] = v;
      tmax = fmaxf(tmax, v);
    }
    tmax = fmaxf(tmax, __shfl_xor(tmax, 16));
    tmax = fmaxf(tmax, __shfl_xor(tmax, 32));
    const float m_new = fmaxf(m_s, tmax);
    const float fsc = __builtin_amdgcn_exp2f((m_s - m_new) * 1.44269504f);
    float psum = 0.0f;
    f16x8 pf0, pf1;  // P lands directly in A-frag layout — no LDS round-trip
#pragma unroll
    for (int cc = 0; cc < 16; ++cc) {
      float pv = __builtin_amdgcn_exp2f((sv[cc] - m_new) * 1.44269504f);
      psum += pv;
      if (cc < 8) pf0[cc & 7] = (f16)pv;
      else        pf1[cc & 7] = (f16)pv;
    }
    psum += __shfl_xor(psum, 16);
    psum += __shfl_xor(psum, 32);
    l_s = l_s * fsc + psum;
    m_s = m_new;

    // rescale O per row (factors via shfl), accumulate PV
    float fr[4];
#pragma unroll
    for (int reg = 0; reg < 4; ++reg) fr[reg] = __shfl(fsc, g * 4 + reg);
#pragma unroll
    for (int t4 = 0; t4 < 4; ++t4) {
#pragma unroll
      for (int reg = 0; reg < 4; ++reg) acc_o[t4][reg] *= fr[reg];
    }
    __builtin_amdgcn_s_setprio(1);
#pragma unroll
    for (int t4 = 0; t4 < 4; ++t4) {
      acc_o[t4] = MFMA16x16x32F(pf0, vf[t4][0], acc_o[t4]);
      acc_o[t4] = MFMA16x16x32F(pf1, vf[t4][1], acc_o[t4]);
    }
    __builtin_amdgcn_s_setprio(0);
  }

  // ---- flash-merge the 4 waves' partials (s_lds reused as obuf) ----
  if (lane < 16) {
    mb[w][lane] = m_s;
    lbuf[w][lane] = l_s;
  }
  __syncthreads();
  const float M = fmaxf(fmaxf(mb[0][cl], mb[1][cl]), fmaxf(mb[2][cl], mb[3][cl]));
  const float sc = __builtin_amdgcn_exp2f((m_s - M) * 1.44269504f);
  float Lt = 0.0f;
#pragma unroll
  for (int ww = 0; ww < 4; ++ww)
    Lt += lbuf[ww][cl] * __builtin_amdgcn_exp2f((mb[ww][cl] - M) * 1.44269504f);
  if (w == 0 && lane < 16) linv[lane] = 1.0f / Lt;
  float fr2[4];
#pragma unroll
  for (int reg = 0; reg < 4; ++reg) fr2[reg] = __shfl(sc, g * 4 + reg);
#pragma unroll
  for (int t4 = 0; t4 < 4; ++t4) {
#pragma unroll
    for (int reg = 0; reg < 4; ++reg)
      s_lds[w][g * 4 + reg][t4 * 16 + cl] = acc_o[t4][reg] * fr2[reg];
  }
  __syncthreads();
  const int bb = bh >> 4;
#pragma unroll
  for (int rep = 0; rep < 4; ++rep) {
    const int o_ = t + rep * 256;
    const int r = o_ >> 6, c = o_ & 63;
    float s = s_lds[0][r][c] + s_lds[1][r][c] + s_lds[2][r][c] + s_lds[3][r][c];
    ao[(size_t)(bb * NL + i0 + r) * ND + h * NHD + c] = (f16)(s * linv[r]);
  }
}

// ---------------- kernel 3: output projection (f16, 64x128 tile, BK=64, T2 swizzle) ----------------
__global__ __launch_bounds__(256) void out_gemm_k(const f16* __restrict__ A,
                                                  const f16* __restrict__ WT,
                                                  const float* __restrict__ bias,
                                                  float* __restrict__ out) {
  __shared__ f16 sA[2][64 * 32], sB[2][128 * 32];
  const int t = threadIdx.x;
  const int lane = t & 63, w = t >> 6;
  const int cl = lane & 15, g = lane >> 4;
  const int m0 = blockIdx.x * 64;
  const int n0 = blockIdx.y * 128;

  const int arow = w * 16 + (lane >> 2);
  const int brow0 = w * 32 + (lane >> 2);
  const int scol = ((lane & 3) ^ ((lane >> 3) & 3)) * 8;
  const int rsw = (g ^ ((cl >> 1) & 3)) * 8;

  f32x4 acc[4][2] = {};

  for (int k0 = 0; k0 < ND; k0 += 64) {
#pragma unroll
    for (int kc = 0; kc < 2; ++kc) {
      const int kk = k0 + kc * 32;
      gload16(A + (size_t)(m0 + arow) * ND + kk + scol, &sA[kc][w * 512]);
      const f16* gb0 = WT + (size_t)(n0 + brow0) * ND + kk + scol;
      gload16(gb0, &sB[kc][w * 1024]);
      gload16(gb0 + (size_t)16 * ND, &sB[kc][w * 1024 + 512]);
    }
    __syncthreads();
#pragma unroll
    for (int kc = 0; kc < 2; ++kc) {
      f16x8 ah[4], bh[2];
#pragma unroll
      for (int fm = 0; fm < 4; ++fm) ah[fm] = *(const f16x8*)&sA[kc][(fm * 16 + cl) * 32 + rsw];
#pragma unroll
      for (int fn = 0; fn < 2; ++fn) bh[fn] = *(const f16x8*)&sB[kc][(w * 32 + fn * 16 + cl) * 32 + rsw];
#pragma unroll
      for (int fm = 0; fm < 4; ++fm)
#pragma unroll
        for (int fn = 0; fn < 2; ++fn)
          acc[fm][fn] = MFMA16x16x32F(ah[fm], bh[fn], acc[fm][fn]);
    }
    __syncthreads();
  }
#pragma unroll
  for (int fm = 0; fm < 4; ++fm) {
#pragma unroll
    for (int fn = 0; fn < 2; ++fn) {
#pragma unroll
      for (int reg = 0; reg < 4; ++reg) {
        const int gm = m0 + fm * 16 + g * 4 + reg;
        const int gn = n0 + w * 32 + fn * 16 + cl;
        out[(size_t)gm * ND + gn] = acc[fm][fn][reg] + bias[gn];
      }
    }
  }
}

extern "C" void kernel_launch(void* const* d_in, const int* in_sizes, int n_in,
                              void* d_out, int out_size, void* d_ws, size_t ws_size,
                              hipStream_t stream) {
  (void)in_sizes; (void)n_in; (void)out_size; (void)ws_size;
  const float* x = (const float*)d_in[0];
  // d_in[1] = causal mask — structural (triu k=1), computed inline
  const float* Wqkv = (const float*)d_in[2];
  const float* bqkv = (const float*)d_in[3];
  const float* Wo = (const float*)d_in[4];
  const float* bo = (const float*)d_in[5];
  const float* Er = (const float*)d_in[6];

  char* ws = (char*)d_ws;
  size_t off = 0;
  auto take = [&](size_t bytes) {
    char* p = ws + off;
    off += (bytes + 255) & ~(size_t)255;
    return p;
  };
  const size_t qkN = (size_t)NBH * NL * NHD;       // 2,097,152
  const size_t xN = (size_t)NB * NL * ND;          // 2,097,152
  const size_t erpN = (size_t)NH * 128 * 2 * 512;  // 2,097,152
  f16* epf = (f16*)take(erpN * 2);
  f16* qfw = (f16*)take(qkN * 2);
  f16* kpw = (f16*)take(qkN * 2);    // K frag-packed
  f16* vpw = (f16*)take(qkN * 2);    // V frag-packed
  f16* wqkvt = (f16*)take((size_t)3 * ND * ND * 2);  // [3072][1024]
  f16* wot   = (f16*)take((size_t)ND * ND * 2);      // [1024][1024]
  f16* xf    = (f16*)take(xN * 2);                   // X f16
  f16* aow = wqkvt;  // alias: wqkvt dead after qkv_gemm, aow born in attn

  prep_all_k<<<17408, 256, 0, stream>>>(Er, epf, x, xf, Wqkv, wqkvt, Wo, wot);
  qkv_gemm_k<<<dim3(24, 32), 256, 0, stream>>>(xf, wqkvt, bqkv, qfw, kpw, vpw);
  attn_k<<<2048, 256, 0, stream>>>(qfw, kpw, vpw, epf, aow);
  out_gemm_k<<<dim3(32, 8), 256, 0, stream>>>(aow, wot, bo, (float*)d_out);
}

// Round 17
// 84.258 us; speedup vs baseline: 1.1815x; 1.0126x over previous
//
#include <hip/hip_runtime.h>

typedef _Float16 f16;
typedef _Float16 f16x8 __attribute__((ext_vector_type(8)));
typedef float f32x4 __attribute__((ext_vector_type(4)));

static_assert(sizeof(f16x8) == 16, "f16x8 must be 16B");

#define MFMA16x16x32F(a, b, c) __builtin_amdgcn_mfma_f32_16x16x32_f16((a), (b), (c), 0, 0, 0)

// problem constants
#define NB 2
#define NL 1024
#define ND 1024
#define NH 16
#define NHD 64
#define NP 2047
#define NBH (NB * NH)  // 32

// wave-synchronous LDS fence (wave-private LDS slices): no vmcnt drain
__device__ __forceinline__ void wave_sync_lds() {
  asm volatile("s_waitcnt lgkmcnt(0)" ::: "memory");
}

// async global->LDS, 16B per lane, wave-linear dest
__device__ __forceinline__ void gload16(const f16* g, f16* lds) {
  __builtin_amdgcn_global_load_lds((const __attribute__((address_space(1))) void*)g,
                                   (__attribute__((address_space(3))) void*)lds, 16, 0, 0);
}

// ---------------- kernel 0: fused prep — Er frag-pack + X cast + both W transposes ----------------
// blocks [0,8192): er_pack; [8192,16384): X cast; [16384,17408): W transposes.
__global__ __launch_bounds__(256) void prep_all_k(const float* __restrict__ er,
                                                  f16* __restrict__ epf,
                                                  const float* __restrict__ x,
                                                  f16* __restrict__ xf,
                                                  const float* __restrict__ Wqkv,
                                                  f16* __restrict__ WTqkv,
                                                  const float* __restrict__ Wo,
                                                  f16* __restrict__ WTo) {
  const int b = blockIdx.x;
  const int t = threadIdx.x;
  if (b < 8192) {
    const int i = b * 256 + t;  // 2^21 total
    const int e = i & 7;
    const int lane = (i >> 3) & 63;
    const int half = (i >> 9) & 1;
    const int ob = (i >> 10) & 127;
    const int h = i >> 17;
    const int g = lane >> 4, cl = lane & 15;
    const int o = ob * 16 - 1024 + cl;
    const int p = (o <= 0) ? -o : (NP - o);
    const int d = half * 32 + g * 8 + e;
    epf[i] = (f16)er[(size_t)(h * NP + p) * NHD + d];
  } else if (b < 16384) {
    const int i = (b - 8192) * 256 + t;
    xf[i] = (f16)x[i];
  } else {
    __shared__ float tile[64][68];
    const int b2 = b - 16384;           // [0,1024)
    const int bx = b2 >> 4;             // [0,64)
    const int k0 = (b2 & 15) * 64;
    const float* W;
    f16* WT;
    int N, n0;
    if (bx < 48) { W = Wqkv; WT = WTqkv; N = 3072; n0 = bx * 64; }
    else         { W = Wo;   WT = WTo;   N = 1024; n0 = (bx - 48) * 64; }
    const int rc = t & 15;
    const int rr0 = t >> 4;
#pragma unroll
    for (int i = 0; i < 4; ++i) {
      const int row = rr0 + i * 16;
      float4 v = *(const float4*)(W + (size_t)(k0 + row) * N + n0 + rc * 4);
      *(float4*)&tile[row][rc * 4] = v;
    }
    __syncthreads();
    const int n = t >> 2, kc = (t & 3) * 16;
    f16x8 h0, h1;
#pragma unroll
    for (int e = 0; e < 8; ++e) h0[e] = (f16)tile[kc + e][n];
#pragma unroll
    for (int e = 0; e < 8; ++e) h1[e] = (f16)tile[kc + 8 + e][n];
    f16* dst = WT + (size_t)(n0 + n) * ND + k0 + kc;
    *(f16x8*)dst = h0;
    *(f16x8*)(dst + 8) = h1;
  }
}

// ---------------- kernel 1: QKV projection GEMM (f16, 64x128 tile, BK=64 as 2x32 sub-tiles) ----------------
__global__ __launch_bounds__(256) void qkv_gemm_k(const f16* __restrict__ Xf,
                                                  const f16* __restrict__ WT,
                                                  const float* __restrict__ bias,
                                                  f16* __restrict__ qf,
                                                  f16* __restrict__ kp, f16* __restrict__ vp) {
  __shared__ f16 sA[2][64 * 32], sB[2][128 * 32];  // 24 KB
  const int t = threadIdx.x;
  const int lane = t & 63;
  const int w = t >> 6;
  const int cl = lane & 15;
  const int g = lane >> 4;
  const int m0 = blockIdx.y * 64;
  const int n0 = blockIdx.x * 128;

  const int arow = w * 16 + (lane >> 2);
  const int brow0 = w * 32 + (lane >> 2);
  const int scol = ((lane & 3) ^ ((lane >> 3) & 3)) * 8;  // T2 source swizzle
  const int rsw = (g ^ ((cl >> 1) & 3)) * 8;              // swizzled read col

  f32x4 acc[4][2] = {};

  for (int k0 = 0; k0 < ND; k0 += 64) {
#pragma unroll
    for (int kc = 0; kc < 2; ++kc) {
      const int kk = k0 + kc * 32;
      gload16(Xf + (size_t)(m0 + arow) * ND + kk + scol, &sA[kc][w * 512]);
      const f16* gb0 = WT + (size_t)(n0 + brow0) * ND + kk + scol;
      gload16(gb0, &sB[kc][w * 1024]);
      gload16(gb0 + (size_t)16 * ND, &sB[kc][w * 1024 + 512]);
    }
    __syncthreads();

#pragma unroll
    for (int kc = 0; kc < 2; ++kc) {
      f16x8 ah[4], bh[2];
#pragma unroll
      for (int fm = 0; fm < 4; ++fm) ah[fm] = *(const f16x8*)&sA[kc][(fm * 16 + cl) * 32 + rsw];
#pragma unroll
      for (int fn = 0; fn < 2; ++fn) bh[fn] = *(const f16x8*)&sB[kc][(w * 32 + fn * 16 + cl) * 32 + rsw];
#pragma unroll
      for (int fm = 0; fm < 4; ++fm)
#pragma unroll
        for (int fn = 0; fn < 2; ++fn)
          acc[fm][fn] = MFMA16x16x32F(ah[fm], bh[fn], acc[fm][fn]);
    }
    __syncthreads();
  }

  // epilogue: bias + scatter into attention layouts (all f16)
#pragma unroll
  for (int fm = 0; fm < 4; ++fm) {
#pragma unroll
    for (int fn = 0; fn < 2; ++fn) {
#pragma unroll
      for (int reg = 0; reg < 4; ++reg) {
        const int gm = m0 + fm * 16 + g * 4 + reg;       // token row
        const int gn = n0 + w * 32 + fn * 16 + cl;       // qkv col
        float val = acc[fm][fn][reg] + bias[gn];
        const int bb = gm >> 10, lpos = gm & 1023;
        const int sec = gn >> 10, hc = gn & 1023;
        const int hh = hc >> 6, dd = hc & 63;
        const int bh = bb * NH + hh;
        if (sec == 0) {
          qf[(size_t)(bh * NL + lpos) * NHD + dd] = (f16)val;
        } else if (sec == 1) {
          const size_t idx = ((size_t)((bh * 64 + (lpos >> 4)) * 2 + (dd >> 5))) * 512 +
                             ((((dd >> 3) & 3) << 4) + (lpos & 15)) * 8 + (dd & 7);
          kp[idx] = (f16)val;
        } else {
          const size_t idx = ((size_t)(((bh * 16 + (lpos >> 6)) * 4 + (dd >> 4)) * 2 +
                                       ((lpos >> 5) & 1))) * 512 +
                             ((((lpos >> 3) & 3) << 4) + (dd & 15)) * 8 + (lpos & 7);
          vp[idx] = (f16)val;
        }
      }
    }
  }
}

// ---------------- kernel 2: attention, v13 (v11 + cross-fence K prefetch) ----------------
__global__ __launch_bounds__(256) void attn_k(const f16* __restrict__ qf,
                                              const f16* __restrict__ kp, const f16* __restrict__ vp,
                                              const f16* __restrict__ epf,
                                              f16* __restrict__ ao) {
  __shared__ float s_lds[4][16][67];
  __shared__ float mb[4][16], lbuf[4][16], linv[16];

  const int t = threadIdx.x;
  const int w = t >> 6;
  const int lane = t & 63;
  const int cl = lane & 15;
  const int g = lane >> 4;

  const int n = blockIdx.x;
  const int xcd = n & 7, idx = n >> 3;
  const int bh = (xcd << 2) | (idx >> 6);
  const int itile = 63 - (idx & 63);
  const int i0 = itile * 16;
  const int h = bh & (NH - 1);
  const int nchunks = (itile >> 2) + 1;

  const f16* qfb = qf + (size_t)(bh * NL + i0 + cl) * NHD + g * 8;
  const f16x8 q_f0 = *(const f16x8*)qfb;
  const f16x8 q_f1 = *(const f16x8*)(qfb + 32);

  f32x4 acc_o[4] = {};
  float m_s = -3e38f, l_s = 0.0f;

  // prefetch first chunk's K tiles jn=0,1 (4 frags, named regs)
  f16x8 kpre0, kpre1, kpre2, kpre3;
  if (w < nchunks) {
    const f16* kb0 = kp + ((size_t)(bh * 64 + ((w * 64) >> 4)) * 2) * 512 + lane * 8;
    kpre0 = *(const f16x8*)(kb0 + 0 * 512);
    kpre1 = *(const f16x8*)(kb0 + 1 * 512);
    kpre2 = *(const f16x8*)(kb0 + 2 * 512);
    kpre3 = *(const f16x8*)(kb0 + 3 * 512);
  }

  for (int jc = w; jc < nchunks; jc += 4) {
    const int j0 = jc * 64;
    const int delta = i0 - j0;

    // ---- V fragments (contiguous 1KB streams) ----
    const f16* vbase = vp + ((size_t)(bh * 16 + (j0 >> 6)) * 8) * 512 + lane * 8;
    f16x8 vf[4][2];
#pragma unroll
    for (int t4 = 0; t4 < 4; ++t4) {
      vf[t4][0] = *(const f16x8*)(vbase + (t4 * 2 + 0) * 512);
      vf[t4][1] = *(const f16x8*)(vbase + (t4 * 2 + 1) * 512);
    }

    // ---- S = Q K^T (jn 0,1 from prefetch; jn 2,3 direct) ----
    const f16* kbase = kp + ((size_t)(bh * 64 + (j0 >> 4)) * 2) * 512 + lane * 8;
    f32x4 acc_s[4];
    __builtin_amdgcn_s_setprio(1);
    {
      f32x4 a = {};
      a = MFMA16x16x32F(q_f0, kpre0, a);
      a = MFMA16x16x32F(q_f1, kpre1, a);
      acc_s[0] = a;
      f32x4 b = {};
      b = MFMA16x16x32F(q_f0, kpre2, b);
      b = MFMA16x16x32F(q_f1, kpre3, b);
      acc_s[1] = b;
    }
#pragma unroll
    for (int jn = 2; jn < 4; ++jn) {
      f16x8 kf0 = *(const f16x8*)(kbase + (jn * 2 + 0) * 512);
      f16x8 kf1 = *(const f16x8*)(kbase + (jn * 2 + 1) * 512);
      f32x4 a = {};
      a = MFMA16x16x32F(q_f0, kf0, a);
      a = MFMA16x16x32F(q_f1, kf1, a);
      acc_s[jn] = a;
    }

    // ---- bias: 5 Er tiles ----
    const int ob0 = (delta >> 4) + 60;
    const f16* ebase = epf + ((size_t)(h * 128 + ob0) * 2) * 512 + lane * 8;
    f32x4 acc_e[5];
#pragma unroll
    for (int tt = 0; tt < 5; ++tt) {
      f16x8 ef0 = *(const f16x8*)(ebase + (tt * 2 + 0) * 512);
      f16x8 ef1 = *(const f16x8*)(ebase + (tt * 2 + 1) * 512);
      f32x4 c = {};
      c = MFMA16x16x32F(q_f0, ef0, c);
      c = MFMA16x16x32F(q_f1, ef1, c);
      acc_e[tt] = c;
    }
    __builtin_amdgcn_s_setprio(0);

    // ---- issue next chunk's K prefetch BEFORE the fence (rides across softmax+PV) ----
    if (jc + 4 < nchunks) {
      const f16* kbn = kp + ((size_t)(bh * 64 + ((j0 + 256) >> 4)) * 2) * 512 + lane * 8;
      kpre0 = *(const f16x8*)(kbn + 0 * 512);
      kpre1 = *(const f16x8*)(kbn + 1 * 512);
      kpre2 = *(const f16x8*)(kbn + 2 * 512);
      kpre3 = *(const f16x8*)(kbn + 3 * 512);
    }

    // ---- in-register diagonal gather of E into S; spill combined to LDS ----
#pragma unroll
    for (int reg = 0; reg < 4; ++reg) {
      const int r = g * 4 + reg;
      const int src = (g << 4) | ((r - cl) & 15);
      const bool ge = (r >= cl);
#pragma unroll
      for (int jn = 0; jn < 4; ++jn) {
        float e_hi = __shfl(acc_e[4 - jn][reg], src);
        float e_lo = __shfl(acc_e[3 - jn][reg], src);
        s_lds[w][r][jn * 16 + cl] = fmaf(acc_s[jn][reg], 0.125f, ge ? e_hi : e_lo);
      }
    }
    wave_sync_lds();

    // ---- online softmax; lane (g,cl): row=cl, cols {g*8+cc} U {32+g*8+cc} ----
    float sv[16];
    float tmax = -3e38f;
#pragma unroll
    for (int cc = 0; cc < 16; ++cc) {
      const int c = (cc < 8) ? (g * 8 + cc) : (32 + g * 8 + (cc - 8));
      float v = s_lds[w][cl][c];
      if (c > delta + cl) v = -3e38f;
      sv[cc] = v;
      tmax = fmaxf(tmax, v);
    }
    tmax = fmaxf(tmax, __shfl_xor(tmax, 16));
    tmax = fmaxf(tmax, __shfl_xor(tmax, 32));
    const float m_new = fmaxf(m_s, tmax);
    const float fsc = __builtin_amdgcn_exp2f((m_s - m_new) * 1.44269504f);
    float psum = 0.0f;
    f16x8 pf0, pf1;  // P lands directly in A-frag layout — no LDS round-trip
#pragma unroll
    for (int cc = 0; cc < 16; ++cc) {
      float pv = __builtin_amdgcn_exp2f((sv[cc] - m_new) * 1.44269504f);
      psum += pv;
      if (cc < 8) pf0[cc & 7] = (f16)pv;
      else        pf1[cc & 7] = (f16)pv;
    }
    psum += __shfl_xor(psum, 16);
    psum += __shfl_xor(psum, 32);
    l_s = l_s * fsc + psum;
    m_s = m_new;

    // rescale O per row (factors via shfl), accumulate PV
    float fr[4];
#pragma unroll
    for (int reg = 0; reg < 4; ++reg) fr[reg] = __shfl(fsc, g * 4 + reg);
#pragma unroll
    for (int t4 = 0; t4 < 4; ++t4) {
#pragma unroll
      for (int reg = 0; reg < 4; ++reg) acc_o[t4][reg] *= fr[reg];
    }
    __builtin_amdgcn_s_setprio(1);
#pragma unroll
    for (int t4 = 0; t4 < 4; ++t4) {
      acc_o[t4] = MFMA16x16x32F(pf0, vf[t4][0], acc_o[t4]);
      acc_o[t4] = MFMA16x16x32F(pf1, vf[t4][1], acc_o[t4]);
    }
    __builtin_amdgcn_s_setprio(0);
  }

  // ---- flash-merge the 4 waves' partials (s_lds reused as obuf) ----
  if (lane < 16) {
    mb[w][lane] = m_s;
    lbuf[w][lane] = l_s;
  }
  __syncthreads();
  const float M = fmaxf(fmaxf(mb[0][cl], mb[1][cl]), fmaxf(mb[2][cl], mb[3][cl]));
  const float sc = __builtin_amdgcn_exp2f((m_s - M) * 1.44269504f);
  float Lt = 0.0f;
#pragma unroll
  for (int ww = 0; ww < 4; ++ww)
    Lt += lbuf[ww][cl] * __builtin_amdgcn_exp2f((mb[ww][cl] - M) * 1.44269504f);
  if (w == 0 && lane < 16) linv[lane] = 1.0f / Lt;
  float fr2[4];
#pragma unroll
  for (int reg = 0; reg < 4; ++reg) fr2[reg] = __shfl(sc, g * 4 + reg);
#pragma unroll
  for (int t4 = 0; t4 < 4; ++t4) {
#pragma unroll
    for (int reg = 0; reg < 4; ++reg)
      s_lds[w][g * 4 + reg][t4 * 16 + cl] = acc_o[t4][reg] * fr2[reg];
  }
  __syncthreads();
  const int bb = bh >> 4;
#pragma unroll
  for (int rep = 0; rep < 4; ++rep) {
    const int o_ = t + rep * 256;
    const int r = o_ >> 6, c = o_ & 63;
    float s = s_lds[0][r][c] + s_lds[1][r][c] + s_lds[2][r][c] + s_lds[3][r][c];
    ao[(size_t)(bb * NL + i0 + r) * ND + h * NHD + c] = (f16)(s * linv[r]);
  }
}

// ---------------- kernel 3: output projection (f16, 32x128 tile, BK=64, 512 blocks) ----------------
__global__ __launch_bounds__(256) void out_gemm_k(const f16* __restrict__ A,
                                                  const f16* __restrict__ WT,
                                                  const float* __restrict__ bias,
                                                  float* __restrict__ out) {
  __shared__ f16 sA[2][32 * 32], sB[2][128 * 32];  // 20 KB
  const int t = threadIdx.x;
  const int lane = t & 63, w = t >> 6;
  const int cl = lane & 15, g = lane >> 4;
  const int m0 = blockIdx.x * 32;
  const int n0 = blockIdx.y * 128;

  const int arow = w * 16 + (lane >> 2);   // valid when w < 2
  const int brow0 = w * 32 + (lane >> 2);
  const int scol = ((lane & 3) ^ ((lane >> 3) & 3)) * 8;
  const int rsw = (g ^ ((cl >> 1) & 3)) * 8;

  f32x4 acc[2][2] = {};

  for (int k0 = 0; k0 < ND; k0 += 64) {
#pragma unroll
    for (int kc = 0; kc < 2; ++kc) {
      const int kk = k0 + kc * 32;
      if (w < 2) gload16(A + (size_t)(m0 + arow) * ND + kk + scol, &sA[kc][w * 512]);
      const f16* gb0 = WT + (size_t)(n0 + brow0) * ND + kk + scol;
      gload16(gb0, &sB[kc][w * 1024]);
      gload16(gb0 + (size_t)16 * ND, &sB[kc][w * 1024 + 512]);
    }
    __syncthreads();
#pragma unroll
    for (int kc = 0; kc < 2; ++kc) {
      f16x8 ah[2], bh[2];
#pragma unroll
      for (int fm = 0; fm < 2; ++fm) ah[fm] = *(const f16x8*)&sA[kc][(fm * 16 + cl) * 32 + rsw];
#pragma unroll
      for (int fn = 0; fn < 2; ++fn) bh[fn] = *(const f16x8*)&sB[kc][(w * 32 + fn * 16 + cl) * 32 + rsw];
#pragma unroll
      for (int fm = 0; fm < 2; ++fm)
#pragma unroll
        for (int fn = 0; fn < 2; ++fn)
          acc[fm][fn] = MFMA16x16x32F(ah[fm], bh[fn], acc[fm][fn]);
    }
    __syncthreads();
  }
#pragma unroll
  for (int fm = 0; fm < 2; ++fm) {
#pragma unroll
    for (int fn = 0; fn < 2; ++fn) {
#pragma unroll
      for (int reg = 0; reg < 4; ++reg) {
        const int gm = m0 + fm * 16 + g * 4 + reg;
        const int gn = n0 + w * 32 + fn * 16 + cl;
        out[(size_t)gm * ND + gn] = acc[fm][fn][reg] + bias[gn];
      }
    }
  }
}

extern "C" void kernel_launch(void* const* d_in, const int* in_sizes, int n_in,
                              void* d_out, int out_size, void* d_ws, size_t ws_size,
                              hipStream_t stream) {
  (void)in_sizes; (void)n_in; (void)out_size; (void)ws_size;
  const float* x = (const float*)d_in[0];
  // d_in[1] = causal mask — structural (triu k=1), computed inline
  const float* Wqkv = (const float*)d_in[2];
  const float* bqkv = (const float*)d_in[3];
  const float* Wo = (const float*)d_in[4];
  const float* bo = (const float*)d_in[5];
  const float* Er = (const float*)d_in[6];

  char* ws = (char*)d_ws;
  size_t off = 0;
  auto take = [&](size_t bytes) {
    char* p = ws + off;
    off += (bytes + 255) & ~(size_t)255;
    return p;
  };
  const size_t qkN = (size_t)NBH * NL * NHD;       // 2,097,152
  const size_t xN = (size_t)NB * NL * ND;          // 2,097,152
  const size_t erpN = (size_t)NH * 128 * 2 * 512;  // 2,097,152
  f16* epf = (f16*)take(erpN * 2);
  f16* qfw = (f16*)take(qkN * 2);
  f16* kpw = (f16*)take(qkN * 2);    // K frag-packed
  f16* vpw = (f16*)take(qkN * 2);    // V frag-packed
  f16* wqkvt = (f16*)take((size_t)3 * ND * ND * 2);  // [3072][1024]
  f16* wot   = (f16*)take((size_t)ND * ND * 2);      // [1024][1024]
  f16* xf    = (f16*)take(xN * 2);                   // X f16
  f16* aow = wqkvt;  // alias: wqkvt dead after qkv_gemm, aow born in attn

  prep_all_k<<<17408, 256, 0, stream>>>(Er, epf, x, xf, Wqkv, wqkvt, Wo, wot);
  qkv_gemm_k<<<dim3(24, 32), 256, 0, stream>>>(xf, wqkvt, bqkv, qfw, kpw, vpw);
  attn_k<<<2048, 256, 0, stream>>>(qfw, kpw, vpw, epf, aow);
  out_gemm_k<<<dim3(64, 8), 256, 0, stream>>>(aow, wot, bo, (float*)d_out);
}